// Round 4
// baseline (352.564 us; speedup 1.0000x reference)
//
#include <hip/hip_runtime.h>

#define N_NODES 50000
#define N_EDGES 800000
#define NGRAPH  128
#define XPITCH  72   // ushort pitch: 72*2=144B, 16B-aligned rows, 2-way (free) banks
#define NB      391  // dst buckets of 128 nodes
#define HEPB    4096
#define NGRP    3125 // 16-node groups (50000/16 exact)

typedef short bf16x8 __attribute__((ext_vector_type(8)));
typedef float f32x4  __attribute__((ext_vector_type(4)));

// ---------------------------------------------------------------------------
// helpers
// ---------------------------------------------------------------------------

__device__ __forceinline__ float atomAddF(float* p, float v) {
#if defined(__gfx950__) || defined(__AMDGCN__)
    return unsafeAtomicAdd(p, v);
#else
    return atomicAdd(p, v);
#endif
}

__device__ __forceinline__ unsigned short f2bf(float x) {  // RNE f32 -> bf16
    unsigned u = __builtin_bit_cast(unsigned, x);
    u += 0x7fffu + ((u >> 16) & 1u);
    return (unsigned short)(u >> 16);
}
__device__ __forceinline__ float bf2f(unsigned short h) {
    return __builtin_bit_cast(float, (unsigned)h << 16);
}

__device__ __forceinline__ f32x4 mk4(float b) { f32x4 a = {b, b, b, b}; return a; }

// One 16x16 tile vs weight mat, A-frags preloaded in regs.
template<int NKC, int KROW>
__device__ __forceinline__ f32x4 w_tile(const bf16x8* a,
                                        const unsigned short* __restrict__ Wm,
                                        int nt, int col, int quad, f32x4 acc) {
    const unsigned short* wp = Wm + (nt * 16 + col) * KROW + quad * 8;
#pragma unroll
    for (int c = 0; c < NKC; ++c) {
        bf16x8 b = *(const bf16x8*)(wp + c * 32);
        acc = __builtin_amdgcn_mfma_f32_16x16x32_bf16(a[c], b, acc, 0, 0, 0);
    }
    return acc;
}

// load A-frags from the block-shared 16-node slice (same addrs all waves ->
// LDS broadcast)
template<int NKC>
__device__ __forceinline__ void a_load(const unsigned short* __restrict__ sl,
                                       int col, int quad, bf16x8* a) {
    a[0] = *(const bf16x8*)(sl + col * XPITCH + quad * 8);
    if (NKC > 1) a[1] = *(const bf16x8*)(sl + col * XPITCH + quad * 8 + 32);
}

// write this wave's 16-col tile back into the shared slice
__device__ __forceinline__ void w_store1(unsigned short* __restrict__ sl,
                                         int wv, int col, int quad, f32x4 acc,
                                         bool relu) {
#pragma unroll
    for (int r = 0; r < 4; ++r) {
        float x = acc[r];
        if (relu) x = fmaxf(x, 0.f);
        sl[(quad * 4 + r) * XPITCH + wv * 16 + col] = f2bf(x);
    }
}

// store this wave's 16-col tile to global rows (node-major bf16[64])
__device__ __forceinline__ void g_store1(unsigned short* __restrict__ g, int gn0,
                                         int wv, int col, int quad, f32x4 acc) {
#pragma unroll
    for (int r = 0; r < 4; ++r) {
        int node = gn0 + quad * 4 + r;
        if (node < N_NODES)
            g[(size_t)node * 64 + wv * 16 + col] = f2bf(acc[r]);
    }
}

// ---------------------------------------------------------------------------
// weight prep (transpose + bf16 into B-operand layout); also zeroes counters
// ---------------------------------------------------------------------------
#define OFF_NW1T  0
#define OFF_NW2T  2048
#define OFF_LYR   6144
#define LYR_SZ    20480
#define OFF_LIN1T 67584
#define OFF_LIN2T 69632
#define WT_TOTAL  70144

__global__ __launch_bounds__(256) void kPrep(
    const float* __restrict__ nW1, const float* __restrict__ nW2,
    const float* __restrict__ lW1, const float* __restrict__ lW2,
    const float* __restrict__ gW1, const float* __restrict__ gW2,
    const float* __restrict__ lin1W, const float* __restrict__ lin2W,
    unsigned short* __restrict__ WT, int* __restrict__ gHist,
    int* __restrict__ rowCnt, int* __restrict__ doneCnt,
    float* __restrict__ out) {
    int i = blockIdx.x * 256 + threadIdx.x;
    if (i < N_NODES) rowCnt[i] = 0;
    if (blockIdx.x == 0) {
        for (int k = threadIdx.x; k < NB; k += 256) gHist[k] = 0;
        for (int k = threadIdx.x; k < NGRAPH * 8; k += 256) out[k] = 0.f;
        if (threadIdx.x == 0) *doneCnt = 0;
    }
    if (i >= WT_TOTAL) return;
    int j = i;
    if (j < 2048) {
        int n = j >> 5, k = j & 31;
        WT[i] = (k < 16) ? f2bf(nW1[k * 64 + n]) : 0;
        return;
    }
    j -= 2048;
    if (j < 4096) {
        int n = j >> 6, k = j & 63;
        WT[i] = f2bf(nW2[k * 64 + n]);
        return;
    }
    j -= 4096;
    if (j < 3 * LYR_SZ) {
        int l = j / LYR_SZ;  j -= l * LYR_SZ;
        int m = j >> 12;     j &= 4095;
        int n = j >> 6, k = j & 63;
        const float* src;
        if (m == 0)      src = lW1 + (size_t)l * 131 * 64;
        else if (m == 1) src = lW1 + (size_t)l * 131 * 64 + 64 * 64;
        else if (m == 2) src = lW2 + (size_t)l * 4096;
        else if (m == 3) src = gW1 + (size_t)l * 4096;
        else             src = gW2 + (size_t)l * 4096;
        WT[i] = f2bf(src[k * 64 + n]);
        return;
    }
    j -= 3 * LYR_SZ;
    if (j < 2048) {
        int n = j >> 6, k = j & 63;
        WT[i] = f2bf(lin1W[k * 32 + n]);
        return;
    }
    j -= 2048;
    {
        int n = j >> 5, k = j & 31;
        WT[i] = (n < 8) ? f2bf(lin2W[k * 8 + n]) : 0;
    }
}

// ---------------------------------------------------------------------------
// kHist: per-node counts (global atomics) + per-bucket counts (LDS->global);
// the LAST block (threadfence + done-counter) folds the 391-bucket scan,
// writing bucketOff. Removes the whole-GPU-idle 1-block scan dispatch.
// ---------------------------------------------------------------------------
__global__ __launch_bounds__(256) void kHist(const int* __restrict__ ei,
                                             int* __restrict__ rowCnt,
                                             int* __restrict__ gHist,
                                             int* __restrict__ bucketOff,
                                             int* __restrict__ doneCnt) {
    __shared__ int h[NB];
    __shared__ int s0[512], s1[512];
    __shared__ int amLast;
    int tid = threadIdx.x;
    for (int i = tid; i < NB; i += 256) h[i] = 0;
    __syncthreads();
    int base = blockIdx.x * HEPB;
#pragma unroll
    for (int k = 0; k < HEPB; k += 256) {
        int e = base + k + tid;
        if (e < N_EDGES) {
            int d = ei[N_EDGES + e];
            atomicAdd(&h[d >> 7], 1);
            atomicAdd(&rowCnt[d], 1);
        }
    }
    __syncthreads();
    for (int i = tid; i < NB; i += 256)
        if (h[i]) atomicAdd(&gHist[i], h[i]);

    // last block scans buckets
    __threadfence();
    if (tid == 0) amLast = (atomicAdd(doneCnt, 1) == (int)gridDim.x - 1);
    __syncthreads();
    if (!amLast) return;
    __threadfence();

    int g0 = 0, g1 = 0;
    for (int e = tid; e < 512; e += 256) {
        int vbk = (e < NB) ? atomicAdd(&gHist[e], 0) : 0;  // coherent read
        if (e < 256) g0 = vbk; else g1 = vbk;
        s0[e] = vbk;
    }
    __syncthreads();
    int* sp = s0; int* dp = s1;
    for (int off = 1; off < 512; off <<= 1) {
        for (int e = tid; e < 512; e += 256)
            dp[e] = sp[e] + ((e >= off) ? sp[e - off] : 0);
        __syncthreads();
        int* t = sp; sp = dp; dp = t;
    }
    for (int e = tid; e < NB; e += 256)
        bucketOff[e] = sp[e] - ((e < 256) ? g0 : g1);
    if (tid == 0) bucketOff[NB] = sp[NB - 1];
}

// ---------------------------------------------------------------------------
// kRowA: merged dispatch. Blocks [0,NB): per-bucket 128-node LDS scan ->
// rowPtr + gCursor. Blocks [NB, NB+NGRP): kA node pipelines (4 waves N-split
// over one 16-node group). Independent halves overlap.
// ---------------------------------------------------------------------------
__global__ __launch_bounds__(256) void kRowA(
    const int* __restrict__ rowCnt, const int* __restrict__ bucketOff,
    int* __restrict__ gCursor, int* __restrict__ rowPtr,
    const float* __restrict__ x, const float* __restrict__ pos,
    const unsigned short* __restrict__ WT,
    const float* __restrict__ nb1, const float* __restrict__ nb2,
    const float* __restrict__ lW1f, const float* __restrict__ lb1,
    unsigned short* __restrict__ u, unsigned short* __restrict__ v) {
    __shared__ int sc0[128], sc1[128];
    __shared__ unsigned short SL[16 * XPITCH];
    __shared__ float pw[48];

    int tid = threadIdx.x;
    if (blockIdx.x < NB) {
        // ---- rowPtr build for bucket b ----
        int b = blockIdx.x;
        int nodeBase = b * 128;
        int nvalid = min(128, N_NODES - nodeBase);
        int c = (tid < nvalid) ? rowCnt[nodeBase + tid] : 0;
        if (tid < 128) sc0[tid] = c;
        __syncthreads();
        int* sp = sc0; int* dp = sc1;
        for (int off = 1; off < 128; off <<= 1) {
            if (tid < 128) dp[tid] = sp[tid] + ((tid >= off) ? sp[tid - off] : 0);
            __syncthreads();
            int* t = sp; sp = dp; dp = t;
        }
        if (tid < nvalid) {
            int pos = bucketOff[b] + sp[tid] - c;   // exclusive prefix
            rowPtr[nodeBase + tid] = pos;
            gCursor[nodeBase + tid] = pos;
        }
        if (b == NB - 1 && tid == 0) rowPtr[N_NODES] = bucketOff[NB];
        return;
    }

    // ---- kA body: one 16-node group, 4 waves N-split ----
    int gn0 = (blockIdx.x - NB) * 16;
    int lane = tid & 63;
    int wv = __builtin_amdgcn_readfirstlane(tid >> 6);
    int col = lane & 15, quad = lane >> 4;

    for (int idx = tid; idx < 512; idx += 256) {
        int m = idx >> 5, k = idx & 31;
        int node = gn0 + m;
        float val = (k < 16 && node < N_NODES) ? x[(size_t)node * 16 + k] : 0.f;
        SL[m * XPITCH + k] = f2bf(val);
    }
    if (tid < 48) {
        int node = gn0 + tid / 3;
        pw[tid] = (node < N_NODES) ? pos[(size_t)node * 3 + tid % 3] : 0.f;
    }
    __syncthreads();

    bf16x8 a[2];
    f32x4 acc;

    a_load<1>(SL, col, quad, a);
    acc = w_tile<1, 32>(a, WT + OFF_NW1T, wv, col, quad, mk4(nb1[wv * 16 + col]));
    __syncthreads();
    w_store1(SL, wv, col, quad, acc, true);
    __syncthreads();

    a_load<2>(SL, col, quad, a);
    acc = w_tile<2, 64>(a, WT + OFF_NW2T, wv, col, quad, mk4(nb2[wv * 16 + col]));
    __syncthreads();
    w_store1(SL, wv, col, quad, acc, false);
    __syncthreads();

    const unsigned short* aT = WT + OFF_LYR;
    const unsigned short* bT = aT + 4096;
    const float* W1c = lW1f + 128 * 64;

    a_load<2>(SL, col, quad, a);
    acc = w_tile<2, 64>(a, aT, wv, col, quad, mk4(0.f));
    g_store1(u, gn0, wv, col, quad, acc);

    int ch = wv * 16 + col;
    acc = w_tile<2, 64>(a, bT, wv, col, quad, mk4(lb1[ch]));
    float w0 = W1c[ch], w1 = W1c[64 + ch], w2 = W1c[128 + ch];
#pragma unroll
    for (int r = 0; r < 4; ++r) {
        int rr = quad * 4 + r;
        acc[r] += pw[rr * 3 + 0] * w0 + pw[rr * 3 + 1] * w1 + pw[rr * 3 + 2] * w2;
    }
    g_store1(v, gn0, wv, col, quad, acc);
}

// ---------------------------------------------------------------------------
// kScatE: direct CSR scatter. pos = atomicAdd(cursor[dst]); srcList[pos]=src.
// One coalesced pass over edges; replaces the LDS bucket-scatter + per-bucket
// counting sort (two full edge passes + packs round-trip).
// ---------------------------------------------------------------------------
__global__ __launch_bounds__(256) void kScatE(const int* __restrict__ ei,
                                              int* __restrict__ gCursor,
                                              unsigned short* __restrict__ srcList) {
    int e = blockIdx.x * 1024 + threadIdx.x;
#pragma unroll
    for (int k = 0; k < 4; ++k, e += 256) {
        if (e < N_EDGES) {
            int s = ei[e];
            int d = ei[N_EDGES + e];
            int pos = atomicAdd(&gCursor[d], 1);
            srcList[pos] = (unsigned short)s;
        }
    }
}

// ---------------------------------------------------------------------------
// kAgg: wave/node, 16 lanes/edge; quarter q owns edges b+4q..b+4q+3
// (stride 16) -> 4 independent ushort4 row-gathers in flight per quarter,
// 16 per wave. Tail via stride-4 loop. shfl_xor(16|32) reduce.
// aggH may alias u (u row read before any write; wave owns row n).
// ---------------------------------------------------------------------------
__global__ __launch_bounds__(256) void kAgg(const int* __restrict__ rowPtr,
                                            const unsigned short* __restrict__ srcList,
                                            const unsigned short* __restrict__ u,
                                            const unsigned short* __restrict__ v,
                                            unsigned short* __restrict__ aggH) {
    int gt = blockIdx.x * 256 + threadIdx.x;
    int n = gt >> 6;
    int lane = gt & 63;
    if (n >= N_NODES) return;
    int sub = lane & 15;
    int q = lane >> 4;

    ushort4 uu = *(const ushort4*)(u + (size_t)n * 64 + sub * 4);
    float u0 = bf2f(uu.x), u1 = bf2f(uu.y), u2 = bf2f(uu.z), u3 = bf2f(uu.w);

    int b = rowPtr[n], e = rowPtr[n + 1];
    int deg = e - b;
    int full16 = deg & ~15;
    float a0 = 0.f, a1 = 0.f, a2 = 0.f, a3 = 0.f;

    for (int g0 = 0; g0 < full16; g0 += 16) {
        int i = b + g0 + 4 * q;
        int s0 = srcList[i];
        int s1 = srcList[i + 1];
        int s2 = srcList[i + 2];
        int s3 = srcList[i + 3];
        ushort4 w0 = *(const ushort4*)(v + (size_t)s0 * 64 + sub * 4);
        ushort4 w1 = *(const ushort4*)(v + (size_t)s1 * 64 + sub * 4);
        ushort4 w2 = *(const ushort4*)(v + (size_t)s2 * 64 + sub * 4);
        ushort4 w3 = *(const ushort4*)(v + (size_t)s3 * 64 + sub * 4);
        a0 += fmaxf(u0 + bf2f(w0.x), 0.f) + fmaxf(u0 + bf2f(w1.x), 0.f)
            + fmaxf(u0 + bf2f(w2.x), 0.f) + fmaxf(u0 + bf2f(w3.x), 0.f);
        a1 += fmaxf(u1 + bf2f(w0.y), 0.f) + fmaxf(u1 + bf2f(w1.y), 0.f)
            + fmaxf(u1 + bf2f(w2.y), 0.f) + fmaxf(u1 + bf2f(w3.y), 0.f);
        a2 += fmaxf(u2 + bf2f(w0.z), 0.f) + fmaxf(u2 + bf2f(w1.z), 0.f)
            + fmaxf(u2 + bf2f(w2.z), 0.f) + fmaxf(u2 + bf2f(w3.z), 0.f);
        a3 += fmaxf(u3 + bf2f(w0.w), 0.f) + fmaxf(u3 + bf2f(w1.w), 0.f)
            + fmaxf(u3 + bf2f(w2.w), 0.f) + fmaxf(u3 + bf2f(w3.w), 0.f);
    }
    for (int i = b + full16 + q; i < e; i += 4) {
        int s0 = srcList[i];
        ushort4 w0 = *(const ushort4*)(v + (size_t)s0 * 64 + sub * 4);
        a0 += fmaxf(u0 + bf2f(w0.x), 0.f);
        a1 += fmaxf(u1 + bf2f(w0.y), 0.f);
        a2 += fmaxf(u2 + bf2f(w0.z), 0.f);
        a3 += fmaxf(u3 + bf2f(w0.w), 0.f);
    }

    a0 += __shfl_xor(a0, 16); a0 += __shfl_xor(a0, 32);
    a1 += __shfl_xor(a1, 16); a1 += __shfl_xor(a1, 32);
    a2 += __shfl_xor(a2, 16); a2 += __shfl_xor(a2, 32);
    a3 += __shfl_xor(a3, 16); a3 += __shfl_xor(a3, 32);

    if (q == 0) {
        ushort4 o;
        o.x = f2bf(a0); o.y = f2bf(a1); o.z = f2bf(a2); o.w = f2bf(a3);
        *(ushort4*)(aggH + (size_t)n * 64 + sub * 4) = o;
    }
}

// ---------------------------------------------------------------------------
// kB (layers 0,1): one 16-node group per block, 4 waves N-split, barriers
// between stages. Reads aggH (=u) rows into LDS, writes new u (own rows,
// after read) and v.
// ---------------------------------------------------------------------------
__global__ __launch_bounds__(256) void kB(
    const float* __restrict__ pos, const int* __restrict__ rowPtr,
    const unsigned short* __restrict__ WT, int l,
    const float* __restrict__ lb2, const float* __restrict__ gb1,
    const float* __restrict__ gb2,
    const float* __restrict__ lW1f_next, const float* __restrict__ b1n,
    unsigned short* __restrict__ u, unsigned short* __restrict__ v) {
    __shared__ unsigned short SL[16 * XPITCH];
    __shared__ float pw[48];
    __shared__ int rp[17];
    int tid = threadIdx.x;
    int lane = tid & 63;
    int wv = __builtin_amdgcn_readfirstlane(tid >> 6);
    int gn0 = blockIdx.x * 16;
    int col = lane & 15, quad = lane >> 4;

    const unsigned short* LYR = WT + OFF_LYR + (size_t)l * LYR_SZ;
    const unsigned short* lW2T = LYR + 2 * 4096;
    const unsigned short* gW1T = LYR + 3 * 4096;
    const unsigned short* gW2T = LYR + 4 * 4096;
    const unsigned short* aTn = WT + OFF_LYR + (size_t)(l + 1) * LYR_SZ;
    const unsigned short* bTn = aTn + 4096;

    const uint4* ag = (const uint4*)(u + (size_t)gn0 * 64);
    if (tid < 128) {
        int m = tid >> 3, sg = tid & 7;
        uint4 d = (gn0 + m < N_NODES) ? ag[tid] : make_uint4(0u, 0u, 0u, 0u);
        *(uint4*)&SL[m * XPITCH + sg * 8] = d;
    }
    if (tid < 48) {
        int node = gn0 + tid / 3;
        pw[tid] = (node < N_NODES) ? pos[(size_t)node * 3 + tid % 3] : 0.f;
    }
    if (tid < 17) rp[tid] = rowPtr[min(gn0 + tid, N_NODES)];
    __syncthreads();

    bf16x8 a[2];
    f32x4 acc;
    float dgr[4];
#pragma unroll
    for (int r = 0; r < 4; ++r)
        dgr[r] = (float)(rp[quad * 4 + r + 1] - rp[quad * 4 + r]);

    {
        float b = lb2[wv * 16 + col];
        f32x4 init = {dgr[0] * b, dgr[1] * b, dgr[2] * b, dgr[3] * b};
        a_load<2>(SL, col, quad, a);
        acc = w_tile<2, 64>(a, lW2T, wv, col, quad, init);
    }
    __syncthreads();
    w_store1(SL, wv, col, quad, acc, false);
    __syncthreads();

    a_load<2>(SL, col, quad, a);
    acc = w_tile<2, 64>(a, gW1T, wv, col, quad, mk4(gb1[wv * 16 + col]));
    __syncthreads();
    w_store1(SL, wv, col, quad, acc, true);
    __syncthreads();

    a_load<2>(SL, col, quad, a);
    acc = w_tile<2, 64>(a, gW2T, wv, col, quad, mk4(gb2[wv * 16 + col]));
    __syncthreads();
    w_store1(SL, wv, col, quad, acc, true);
    __syncthreads();

    a_load<2>(SL, col, quad, a);
    acc = w_tile<2, 64>(a, aTn, wv, col, quad, mk4(0.f));
    g_store1(u, gn0, wv, col, quad, acc);

    const float* W1c = lW1f_next + 128 * 64;
    int ch = wv * 16 + col;
    acc = w_tile<2, 64>(a, bTn, wv, col, quad, mk4(b1n[ch]));
    float w0 = W1c[ch], w1 = W1c[64 + ch], w2 = W1c[128 + ch];
#pragma unroll
    for (int r = 0; r < 4; ++r) {
        int rr = quad * 4 + r;
        acc[r] += pw[rr * 3 + 0] * w0 + pw[rr * 3 + 1] * w1 + pw[rr * 3 + 2] * w2;
    }
    g_store1(v, gn0, wv, col, quad, acc);
}

// ---------------------------------------------------------------------------
// kC (layer 2): one 16-node group per block, 4 waves N-split + readout bins
// ---------------------------------------------------------------------------
__global__ __launch_bounds__(256) void kC(
    const int* __restrict__ rowPtr, const int* __restrict__ batch,
    const unsigned short* __restrict__ WT,
    const float* __restrict__ lb2, const float* __restrict__ gb1,
    const float* __restrict__ gb2,
    const float* __restrict__ lin1b, const float* __restrict__ lin2b,
    const unsigned short* __restrict__ u, float* __restrict__ out) {
    __shared__ unsigned short SL[16 * XPITCH];
    __shared__ int rp[17];
    __shared__ int batchW[16];
    __shared__ float bins[16 * 8];
    int tid = threadIdx.x;
    int lane = tid & 63;
    int wv = __builtin_amdgcn_readfirstlane(tid >> 6);
    int gn0 = blockIdx.x * 16;   // N_NODES % 16 == 0: all groups full
    int col = lane & 15, quad = lane >> 4;

    const unsigned short* LYR = WT + OFF_LYR + 2 * LYR_SZ;
    const unsigned short* lW2T = LYR + 2 * 4096;
    const unsigned short* gW1T = LYR + 3 * 4096;
    const unsigned short* gW2T = LYR + 4 * 4096;
    const unsigned short* lin1T = WT + OFF_LIN1T;
    const unsigned short* lin2T = WT + OFF_LIN2T;

    const uint4* ag = (const uint4*)(u + (size_t)gn0 * 64);
    if (tid < 128) {
        int m = tid >> 3, sg = tid & 7;
        *(uint4*)&SL[m * XPITCH + sg * 8] = ag[tid];
    }
    if (tid < 17) rp[tid] = rowPtr[gn0 + tid];
    if (tid < 16) batchW[tid] = batch[gn0 + tid];
    if (tid >= 128 && tid < 256) bins[tid - 128] = 0.f;
    __syncthreads();

    bf16x8 a[2];
    f32x4 acc;
    float dgr[4];
#pragma unroll
    for (int r = 0; r < 4; ++r)
        dgr[r] = (float)(rp[quad * 4 + r + 1] - rp[quad * 4 + r]);

    {
        float b = lb2[wv * 16 + col];
        f32x4 init = {dgr[0] * b, dgr[1] * b, dgr[2] * b, dgr[3] * b};
        a_load<2>(SL, col, quad, a);
        acc = w_tile<2, 64>(a, lW2T, wv, col, quad, init);
    }
    __syncthreads();
    w_store1(SL, wv, col, quad, acc, false);
    __syncthreads();

    a_load<2>(SL, col, quad, a);
    acc = w_tile<2, 64>(a, gW1T, wv, col, quad, mk4(gb1[wv * 16 + col]));
    __syncthreads();
    w_store1(SL, wv, col, quad, acc, true);
    __syncthreads();

    a_load<2>(SL, col, quad, a);
    acc = w_tile<2, 64>(a, gW2T, wv, col, quad, mk4(gb2[wv * 16 + col]));
    __syncthreads();
    w_store1(SL, wv, col, quad, acc, true);
    __syncthreads();

    // lin1: 32 output cols -> waves 0,1 only
    a_load<2>(SL, col, quad, a);
    if (wv < 2)
        acc = w_tile<2, 64>(a, lin1T, wv, col, quad, mk4(lin1b[wv * 16 + col]));
    __syncthreads();
    if (wv < 2) w_store1(SL, wv, col, quad, acc, true);
    __syncthreads();

    // lin2: 8 output cols -> wave 0 only; accumulate into per-block bins
    if (wv == 0) {
        a_load<1>(SL, col, quad, a);
        f32x4 o = w_tile<1, 32>(a, lin2T, 0, col, quad,
                                mk4(col < 8 ? lin2b[col] : 0.f));
        int gmin = batchW[0];
        if (col < 8) {
#pragma unroll
            for (int r = 0; r < 4; ++r) {
                int nl = quad * 4 + r;
                atomicAdd(&bins[(batchW[nl] - gmin) * 8 + col], o[r]);
            }
        }
    }
    __syncthreads();
    int gmin = batchW[0];
    int nb8 = (batchW[15] - gmin + 1) * 8;
    for (int idx = tid; idx < nb8; idx += 256)
        atomAddF(&out[gmin * 8 + idx], bins[idx]);
}

// ---------------------------------------------------------------------------
// launch
// ---------------------------------------------------------------------------
extern "C" void kernel_launch(void* const* d_in, const int* in_sizes, int n_in,
                              void* d_out, int out_size, void* d_ws, size_t ws_size,
                              hipStream_t stream) {
    const float* x     = (const float*)d_in[0];
    const float* pos   = (const float*)d_in[1];
    const int*   ei    = (const int*)d_in[2];
    const int*   batch = (const int*)d_in[3];
    const float* nW1   = (const float*)d_in[4];
    const float* nb1   = (const float*)d_in[5];
    const float* nW2   = (const float*)d_in[6];
    const float* nb2   = (const float*)d_in[7];
    const float* lW1   = (const float*)d_in[8];
    const float* lb1   = (const float*)d_in[9];
    const float* lW2   = (const float*)d_in[10];
    const float* lb2   = (const float*)d_in[11];
    const float* gW1   = (const float*)d_in[12];
    const float* gb1   = (const float*)d_in[13];
    const float* gW2   = (const float*)d_in[14];
    const float* gb2   = (const float*)d_in[15];
    const float* lin1W = (const float*)d_in[16];
    const float* lin1b = (const float*)d_in[17];
    const float* lin2W = (const float*)d_in[18];
    const float* lin2b = (const float*)d_in[19];
    float* out = (float*)d_out;

    // workspace (u doubles as aggH)
    unsigned short* u  = (unsigned short*)d_ws;          // N*64 bf16
    unsigned short* v  = u + (size_t)N_NODES * 64;       // N*64 bf16
    unsigned short* WT = v + (size_t)N_NODES * 64;       // WT_TOTAL bf16
    int* gHist = (int*)(WT + WT_TOTAL);                  // NB
    int* bucketOff = gHist + NB;                         // NB+1
    int* rowCnt = bucketOff + NB + 1;                    // N
    int* gCursor = rowCnt + N_NODES;                     // N
    int* rowPtr = gCursor + N_NODES;                     // N+1
    int* doneCnt = rowPtr + N_NODES + 1;                 // 1
    unsigned short* srcList = (unsigned short*)(doneCnt + 1); // E ushort
    unsigned short* aggH = u;

    const int aggBlocks = (N_NODES * 64 + 255) / 256;

    kPrep<<<(WT_TOTAL + 255) / 256, 256, 0, stream>>>(nW1, nW2, lW1, lW2, gW1, gW2,
                                                      lin1W, lin2W, WT, gHist,
                                                      rowCnt, doneCnt, out);
    kHist<<<(N_EDGES + HEPB - 1) / HEPB, 256, 0, stream>>>(ei, rowCnt, gHist,
                                                           bucketOff, doneCnt);
    kRowA<<<NB + NGRP, 256, 0, stream>>>(rowCnt, bucketOff, gCursor, rowPtr,
                                         x, pos, WT, nb1, nb2, lW1, lb1, u, v);
    kScatE<<<(N_EDGES + 1023) / 1024, 256, 0, stream>>>(ei, gCursor, srcList);

    for (int l = 0; l < 3; ++l) {
        kAgg<<<aggBlocks, 256, 0, stream>>>(rowPtr, srcList, u, v, aggH);
        if (l < 2) {
            kB<<<NGRP, 256, 0, stream>>>(
                pos, rowPtr, WT, l,
                lb2 + l * 64, gb1 + l * 64, gb2 + l * 64,
                lW1 + (size_t)(l + 1) * 131 * 64, lb1 + (l + 1) * 64,
                u, v);
        } else {
            kC<<<NGRP, 256, 0, stream>>>(
                rowPtr, batch, WT,
                lb2 + l * 64, gb1 + l * 64, gb2 + l * 64,
                lin1b, lin2b, u, out);
        }
    }
}

// Round 5
// 276.320 us; speedup vs baseline: 1.2759x; 1.2759x over previous
//
#include <hip/hip_runtime.h>

#define N_NODES 50000
#define N_EDGES 800000
#define NGRAPH  128
#define XPITCH  72   // ushort pitch: 72*2=144B, 16B-aligned rows, 2-way (free) banks
#define NB      391  // dst buckets of 128 nodes
#define HEPB    4096
#define SEPB    8192
#define NGRP    3125 // 16-node groups (50000/16 exact)

typedef short bf16x8 __attribute__((ext_vector_type(8)));
typedef float f32x4  __attribute__((ext_vector_type(4)));

// ---------------------------------------------------------------------------
// helpers
// ---------------------------------------------------------------------------

__device__ __forceinline__ float atomAddF(float* p, float v) {
#if defined(__gfx950__) || defined(__AMDGCN__)
    return unsafeAtomicAdd(p, v);
#else
    return atomicAdd(p, v);
#endif
}

__device__ __forceinline__ unsigned short f2bf(float x) {  // RNE f32 -> bf16
    unsigned u = __builtin_bit_cast(unsigned, x);
    u += 0x7fffu + ((u >> 16) & 1u);
    return (unsigned short)(u >> 16);
}
__device__ __forceinline__ float bf2f(unsigned short h) {
    return __builtin_bit_cast(float, (unsigned)h << 16);
}

__device__ __forceinline__ f32x4 mk4(float b) { f32x4 a = {b, b, b, b}; return a; }

// One 16x16 tile vs weight mat, A-frags preloaded in regs.
template<int NKC, int KROW>
__device__ __forceinline__ f32x4 w_tile(const bf16x8* a,
                                        const unsigned short* __restrict__ Wm,
                                        int nt, int col, int quad, f32x4 acc) {
    const unsigned short* wp = Wm + (nt * 16 + col) * KROW + quad * 8;
#pragma unroll
    for (int c = 0; c < NKC; ++c) {
        bf16x8 b = *(const bf16x8*)(wp + c * 32);
        acc = __builtin_amdgcn_mfma_f32_16x16x32_bf16(a[c], b, acc, 0, 0, 0);
    }
    return acc;
}

// load A-frags from the block-shared 16-node slice
template<int NKC>
__device__ __forceinline__ void a_load(const unsigned short* __restrict__ sl,
                                       int col, int quad, bf16x8* a) {
    a[0] = *(const bf16x8*)(sl + col * XPITCH + quad * 8);
    if (NKC > 1) a[1] = *(const bf16x8*)(sl + col * XPITCH + quad * 8 + 32);
}

// write this wave's 16-col tile back into the shared slice
__device__ __forceinline__ void w_store1(unsigned short* __restrict__ sl,
                                         int wv, int col, int quad, f32x4 acc,
                                         bool relu) {
#pragma unroll
    for (int r = 0; r < 4; ++r) {
        float x = acc[r];
        if (relu) x = fmaxf(x, 0.f);
        sl[(quad * 4 + r) * XPITCH + wv * 16 + col] = f2bf(x);
    }
}

// store this wave's 16-col tile to global rows (node-major bf16[64])
__device__ __forceinline__ void g_store1(unsigned short* __restrict__ g, int gn0,
                                         int wv, int col, int quad, f32x4 acc) {
#pragma unroll
    for (int r = 0; r < 4; ++r) {
        int node = gn0 + quad * 4 + r;
        if (node < N_NODES)
            g[(size_t)node * 64 + wv * 16 + col] = f2bf(acc[r]);
    }
}

// ---------------------------------------------------------------------------
// per-wave fused aggregation: wave handles nodes gn0+4*wv .. gn0+4*wv+3.
// agg[c] = sum_e relu(u[c] + vin[src_e][c]); result -> SL row (bf16).
// Round-0 proven inner loop: 16 lanes/edge, quarter q owns edges b+4q..b+4q+3
// (stride 16), shfl_xor(16|32) reduce, quad 0 writes.
// ---------------------------------------------------------------------------
__device__ __forceinline__ void wave_agg4(const int* rp, unsigned short* __restrict__ sl,
                                          const unsigned short* __restrict__ u,
                                          const unsigned short* __restrict__ vin,
                                          const unsigned short* __restrict__ srcList,
                                          int gn0, int wv, int lane) {
    int sub = lane & 15, q = lane >> 4;
#pragma unroll
    for (int mi = 0; mi < 4; ++mi) {
        int m = wv * 4 + mi;
        int n = gn0 + m;
        ushort4 uu = *(const ushort4*)(u + (size_t)n * 64 + sub * 4);
        float u0 = bf2f(uu.x), u1 = bf2f(uu.y), u2 = bf2f(uu.z), u3 = bf2f(uu.w);
        int b = rp[m], e = rp[m + 1];
        int deg = e - b;
        int full16 = deg & ~15;
        float a0 = 0.f, a1 = 0.f, a2 = 0.f, a3 = 0.f;

        for (int g0 = 0; g0 < full16; g0 += 16) {
            int i = b + g0 + 4 * q;
            int s0 = srcList[i];
            int s1 = srcList[i + 1];
            int s2 = srcList[i + 2];
            int s3 = srcList[i + 3];
            ushort4 w0 = *(const ushort4*)(vin + (size_t)s0 * 64 + sub * 4);
            ushort4 w1 = *(const ushort4*)(vin + (size_t)s1 * 64 + sub * 4);
            ushort4 w2 = *(const ushort4*)(vin + (size_t)s2 * 64 + sub * 4);
            ushort4 w3 = *(const ushort4*)(vin + (size_t)s3 * 64 + sub * 4);
            a0 += fmaxf(u0 + bf2f(w0.x), 0.f) + fmaxf(u0 + bf2f(w1.x), 0.f)
                + fmaxf(u0 + bf2f(w2.x), 0.f) + fmaxf(u0 + bf2f(w3.x), 0.f);
            a1 += fmaxf(u1 + bf2f(w0.y), 0.f) + fmaxf(u1 + bf2f(w1.y), 0.f)
                + fmaxf(u1 + bf2f(w2.y), 0.f) + fmaxf(u1 + bf2f(w3.y), 0.f);
            a2 += fmaxf(u2 + bf2f(w0.z), 0.f) + fmaxf(u2 + bf2f(w1.z), 0.f)
                + fmaxf(u2 + bf2f(w2.z), 0.f) + fmaxf(u2 + bf2f(w3.z), 0.f);
            a3 += fmaxf(u3 + bf2f(w0.w), 0.f) + fmaxf(u3 + bf2f(w1.w), 0.f)
                + fmaxf(u3 + bf2f(w2.w), 0.f) + fmaxf(u3 + bf2f(w3.w), 0.f);
        }
        for (int i = b + full16 + q; i < e; i += 4) {
            int s0 = srcList[i];
            ushort4 w0 = *(const ushort4*)(vin + (size_t)s0 * 64 + sub * 4);
            a0 += fmaxf(u0 + bf2f(w0.x), 0.f);
            a1 += fmaxf(u1 + bf2f(w0.y), 0.f);
            a2 += fmaxf(u2 + bf2f(w0.z), 0.f);
            a3 += fmaxf(u3 + bf2f(w0.w), 0.f);
        }

        a0 += __shfl_xor(a0, 16); a0 += __shfl_xor(a0, 32);
        a1 += __shfl_xor(a1, 16); a1 += __shfl_xor(a1, 32);
        a2 += __shfl_xor(a2, 16); a2 += __shfl_xor(a2, 32);
        a3 += __shfl_xor(a3, 16); a3 += __shfl_xor(a3, 32);

        if (q == 0) {
            ushort4 o;
            o.x = f2bf(a0); o.y = f2bf(a1); o.z = f2bf(a2); o.w = f2bf(a3);
            *(ushort4*)&sl[m * XPITCH + sub * 4] = o;
        }
    }
}

// ---------------------------------------------------------------------------
// weight prep (transpose + bf16 into B-operand layout); also zeroes counters
// ---------------------------------------------------------------------------
#define OFF_NW1T  0
#define OFF_NW2T  2048
#define OFF_LYR   6144
#define LYR_SZ    20480
#define OFF_LIN1T 67584
#define OFF_LIN2T 69632
#define WT_TOTAL  70144

__global__ __launch_bounds__(256) void kPrep(
    const float* __restrict__ nW1, const float* __restrict__ nW2,
    const float* __restrict__ lW1, const float* __restrict__ lW2,
    const float* __restrict__ gW1, const float* __restrict__ gW2,
    const float* __restrict__ lin1W, const float* __restrict__ lin2W,
    unsigned short* __restrict__ WT, int* __restrict__ gHist,
    int* __restrict__ doneCnt, float* __restrict__ out) {
    int i = blockIdx.x * 256 + threadIdx.x;
    if (blockIdx.x == 0) {
        for (int k = threadIdx.x; k < NB; k += 256) gHist[k] = 0;
        for (int k = threadIdx.x; k < NGRAPH * 8; k += 256) out[k] = 0.f;
        if (threadIdx.x == 0) *doneCnt = 0;
    }
    if (i >= WT_TOTAL) return;
    int j = i;
    if (j < 2048) {
        int n = j >> 5, k = j & 31;
        WT[i] = (k < 16) ? f2bf(nW1[k * 64 + n]) : 0;
        return;
    }
    j -= 2048;
    if (j < 4096) {
        int n = j >> 6, k = j & 63;
        WT[i] = f2bf(nW2[k * 64 + n]);
        return;
    }
    j -= 4096;
    if (j < 3 * LYR_SZ) {
        int l = j / LYR_SZ;  j -= l * LYR_SZ;
        int m = j >> 12;     j &= 4095;
        int n = j >> 6, k = j & 63;
        const float* src;
        if (m == 0)      src = lW1 + (size_t)l * 131 * 64;
        else if (m == 1) src = lW1 + (size_t)l * 131 * 64 + 64 * 64;
        else if (m == 2) src = lW2 + (size_t)l * 4096;
        else if (m == 3) src = gW1 + (size_t)l * 4096;
        else             src = gW2 + (size_t)l * 4096;
        WT[i] = f2bf(src[k * 64 + n]);
        return;
    }
    j -= 3 * LYR_SZ;
    if (j < 2048) {
        int n = j >> 6, k = j & 63;
        WT[i] = f2bf(lin1W[k * 32 + n]);
        return;
    }
    j -= 2048;
    {
        int n = j >> 5, k = j & 31;
        WT[i] = (n < 8) ? f2bf(lin2W[k * 8 + n]) : 0;
    }
}

// ---------------------------------------------------------------------------
// kHist: LDS bucket hist -> gHist atomics (per-bucket, cheap). The LAST block
// (threadfence + done-counter) scans the 391 buckets and writes bucketOff +
// cursor, folding the old 1-block kScanB dispatch (and its GPU-wide bubble).
// ---------------------------------------------------------------------------
__global__ __launch_bounds__(256) void kHist(const int* __restrict__ ei,
                                             int* __restrict__ gHist,
                                             int* __restrict__ bucketOff,
                                             int* __restrict__ cursor,
                                             int* __restrict__ doneCnt) {
    __shared__ int h[NB];
    __shared__ int s0[512], s1[512];
    __shared__ int amLast;
    int tid = threadIdx.x;
    for (int i = tid; i < NB; i += 256) h[i] = 0;
    __syncthreads();
    int base = blockIdx.x * HEPB;
#pragma unroll
    for (int k = 0; k < HEPB; k += 256) {
        int e = base + k + tid;
        if (e < N_EDGES) atomicAdd(&h[ei[N_EDGES + e] >> 7], 1);
    }
    __syncthreads();
    for (int i = tid; i < NB; i += 256)
        if (h[i]) atomicAdd(&gHist[i], h[i]);

    __threadfence();
    if (tid == 0) amLast = (atomicAdd(doneCnt, 1) == (int)gridDim.x - 1);
    __syncthreads();
    if (!amLast) return;
    __threadfence();

    for (int e = tid; e < 512; e += 256)
        s0[e] = (e < NB) ? atomicAdd(&gHist[e], 0) : 0;  // coherent read
    __syncthreads();
    int* sp = s0; int* dp = s1;
    for (int off = 1; off < 512; off <<= 1) {
        for (int e = tid; e < 512; e += 256)
            dp[e] = sp[e] + ((e >= off) ? sp[e - off] : 0);
        __syncthreads();
        int* t = sp; sp = dp; dp = t;
    }
    for (int e = tid; e < NB; e += 256) {
        int cnt = (e < NB) ? atomicAdd(&gHist[e], 0) : 0;
        int excl = sp[e] - cnt;
        bucketOff[e] = excl;
        cursor[e] = excl;
    }
    if (tid == 0) bucketOff[NB] = sp[NB - 1];
}

__global__ __launch_bounds__(256) void kScat(const int* __restrict__ ei,
                                             int* __restrict__ cursor,
                                             int* __restrict__ packs) {
    __shared__ int sdata[SEPB];
    __shared__ int hist[NB];
    __shared__ int loff[NB + 1];
    __shared__ int gbase[NB];
    __shared__ int sc0[512], sc1[512];
    int tid = threadIdx.x;
    int base = blockIdx.x * SEPB;
    int nE = min(SEPB, N_EDGES - base);

    for (int i = tid; i < NB; i += 256) hist[i] = 0;
    __syncthreads();

    int myPack[SEPB / 256];
    unsigned short myRank[SEPB / 256];
#pragma unroll
    for (int kk = 0; kk < SEPB / 256; ++kk) {
        int e = base + kk * 256 + tid;
        if (e < N_EDGES) {
            int s = ei[e], d = ei[N_EDGES + e];
            myPack[kk] = (s << 16) | d;
            myRank[kk] = (unsigned short)atomicAdd(&hist[d >> 7], 1);
        }
    }
    __syncthreads();

    for (int e = tid; e < 512; e += 256) sc0[e] = (e < NB) ? hist[e] : 0;
    __syncthreads();
    int* sp = sc0; int* dp = sc1;
    for (int off = 1; off < 512; off <<= 1) {
        for (int e = tid; e < 512; e += 256)
            dp[e] = sp[e] + ((e >= off) ? sp[e - off] : 0);
        __syncthreads();
        int* t = sp; sp = dp; dp = t;
    }
    for (int e = tid; e < NB; e += 256) loff[e] = sp[e] - hist[e];
    if (tid == 0) loff[NB] = sp[NB - 1];
    __syncthreads();

    for (int e = tid; e < NB; e += 256)
        gbase[e] = hist[e] ? atomicAdd(&cursor[e], hist[e]) : 0;
#pragma unroll
    for (int kk = 0; kk < SEPB / 256; ++kk) {
        int e = base + kk * 256 + tid;
        if (e < N_EDGES) {
            int p = myPack[kk];
            int b = (p & 0xffff) >> 7;
            sdata[loff[b] + myRank[kk]] = p;
        }
    }
    __syncthreads();

    for (int i = tid; i < nE; i += 256) {
        int p = sdata[i];
        int b = (p & 0xffff) >> 7;
        packs[gbase[b] + (i - loff[b])] = p;
    }
}

// ---------------------------------------------------------------------------
// kSortA: merged dispatch. Blocks [0,NB): per-bucket counting sort.
// Blocks [NB, NB+NGRP): kA node pipelines (4 waves N-split over one 16-node
// group). Independent halves overlap.
// ---------------------------------------------------------------------------
__global__ __launch_bounds__(256) void kSortA(
    const int* __restrict__ bucketOff, const int* __restrict__ packs,
    unsigned short* __restrict__ srcList, int* __restrict__ rowPtr,
    const float* __restrict__ x, const float* __restrict__ pos,
    const unsigned short* __restrict__ WT,
    const float* __restrict__ nb1, const float* __restrict__ nb2,
    const float* __restrict__ lW1f, const float* __restrict__ lb1,
    unsigned short* __restrict__ u, unsigned short* __restrict__ v) {
    __shared__ int hist[128];
    __shared__ int cur[128];
    __shared__ int sc0[128], sc1[128];
    __shared__ unsigned short SL[16 * XPITCH];
    __shared__ float pw[48];

    int tid = threadIdx.x;
    if (blockIdx.x < NB) {
        int nbk = blockIdx.x;
        int nodeBase = nbk * 128;
        int nvalid = min(128, N_NODES - nodeBase);
        int eb = bucketOff[nbk], ee = bucketOff[nbk + 1];

        if (tid < 128) hist[tid] = 0;
        __syncthreads();
        for (int i = eb + tid; i < ee; i += 256)
            atomicAdd(&hist[packs[i] & 127], 1);
        __syncthreads();

        if (tid < 128) sc0[tid] = hist[tid];
        __syncthreads();
        int* sp = sc0; int* dp = sc1;
        for (int off = 1; off < 128; off <<= 1) {
            if (tid < 128) dp[tid] = sp[tid] + ((tid >= off) ? sp[tid - off] : 0);
            __syncthreads();
            int* t = sp; sp = dp; dp = t;
        }
        if (tid < 128) {
            int excl = eb + sp[tid] - hist[tid];
            if (tid < nvalid) rowPtr[nodeBase + tid] = excl;
            cur[tid] = excl;
        }
        if (nbk == NB - 1 && tid == 0) rowPtr[N_NODES] = ee;
        __syncthreads();

        for (int i = eb + tid; i < ee; i += 256) {
            int p = packs[i];
            int ps = atomicAdd(&cur[p & 127], 1);
            srcList[ps] = (unsigned short)(((unsigned)p) >> 16);
        }
        return;
    }

    // ---- kA body: one 16-node group, 4 waves N-split ----
    int gn0 = (blockIdx.x - NB) * 16;
    int lane = tid & 63;
    int wv = __builtin_amdgcn_readfirstlane(tid >> 6);
    int col = lane & 15, quad = lane >> 4;

    for (int idx = tid; idx < 512; idx += 256) {
        int m = idx >> 5, k = idx & 31;
        int node = gn0 + m;
        float val = (k < 16 && node < N_NODES) ? x[(size_t)node * 16 + k] : 0.f;
        SL[m * XPITCH + k] = f2bf(val);
    }
    if (tid < 48) {
        int node = gn0 + tid / 3;
        pw[tid] = (node < N_NODES) ? pos[(size_t)node * 3 + tid % 3] : 0.f;
    }
    __syncthreads();

    bf16x8 a[2];
    f32x4 acc;

    a_load<1>(SL, col, quad, a);
    acc = w_tile<1, 32>(a, WT + OFF_NW1T, wv, col, quad, mk4(nb1[wv * 16 + col]));
    __syncthreads();
    w_store1(SL, wv, col, quad, acc, true);
    __syncthreads();

    a_load<2>(SL, col, quad, a);
    acc = w_tile<2, 64>(a, WT + OFF_NW2T, wv, col, quad, mk4(nb2[wv * 16 + col]));
    __syncthreads();
    w_store1(SL, wv, col, quad, acc, false);
    __syncthreads();

    const unsigned short* aT = WT + OFF_LYR;
    const unsigned short* bT = aT + 4096;
    const float* W1c = lW1f + 128 * 64;

    a_load<2>(SL, col, quad, a);
    acc = w_tile<2, 64>(a, aT, wv, col, quad, mk4(0.f));
    g_store1(u, gn0, wv, col, quad, acc);

    int ch = wv * 16 + col;
    acc = w_tile<2, 64>(a, bT, wv, col, quad, mk4(lb1[ch]));
    float w0 = W1c[ch], w1 = W1c[64 + ch], w2 = W1c[128 + ch];
#pragma unroll
    for (int r = 0; r < 4; ++r) {
        int rr = quad * 4 + r;
        acc[r] += pw[rr * 3 + 0] * w0 + pw[rr * 3 + 1] * w1 + pw[rr * 3 + 2] * w2;
    }
    g_store1(v, gn0, wv, col, quad, acc);
}

// ---------------------------------------------------------------------------
// kB (layers 0,1): fused per-wave aggregation (4 nodes/wave) + 4-wave N-split
// GEMM chain. 3125 blocks -> ~32 waves/CU: agg phase is BW-bound, not
// latency-bound (round-1's failure was 12 waves/CU). u in-place (all agg-phase
// reads precede the post-barrier writes; other blocks never touch our rows);
// v ping-pong (vin read-only, vout written).
// ---------------------------------------------------------------------------
__global__ __launch_bounds__(256) void kB(
    const float* __restrict__ pos, const int* __restrict__ rowPtr,
    const unsigned short* __restrict__ srcList,
    const unsigned short* __restrict__ WT, int l,
    const float* __restrict__ lb2, const float* __restrict__ gb1,
    const float* __restrict__ gb2,
    const float* __restrict__ lW1f_next, const float* __restrict__ b1n,
    unsigned short* __restrict__ u,
    const unsigned short* __restrict__ vin,
    unsigned short* __restrict__ vout) {
    __shared__ unsigned short SL[16 * XPITCH];
    __shared__ float pw[48];
    __shared__ int rp[17];
    int tid = threadIdx.x;
    int lane = tid & 63;
    int wv = __builtin_amdgcn_readfirstlane(tid >> 6);
    int gn0 = blockIdx.x * 16;   // N_NODES % 16 == 0
    int col = lane & 15, quad = lane >> 4;

    const unsigned short* LYR = WT + OFF_LYR + (size_t)l * LYR_SZ;
    const unsigned short* lW2T = LYR + 2 * 4096;
    const unsigned short* gW1T = LYR + 3 * 4096;
    const unsigned short* gW2T = LYR + 4 * 4096;
    const unsigned short* aTn = WT + OFF_LYR + (size_t)(l + 1) * LYR_SZ;
    const unsigned short* bTn = aTn + 4096;

    if (tid < 48) {
        int node = gn0 + tid / 3;
        pw[tid] = pos[(size_t)node * 3 + tid % 3];
    }
    if (tid < 17) rp[tid] = rowPtr[gn0 + tid];
    __syncthreads();

    wave_agg4(rp, SL, u, vin, srcList, gn0, wv, lane);
    __syncthreads();

    bf16x8 a[2];
    f32x4 acc;
    float dgr[4];
#pragma unroll
    for (int r = 0; r < 4; ++r)
        dgr[r] = (float)(rp[quad * 4 + r + 1] - rp[quad * 4 + r]);

    {
        float b = lb2[wv * 16 + col];
        f32x4 init = {dgr[0] * b, dgr[1] * b, dgr[2] * b, dgr[3] * b};
        a_load<2>(SL, col, quad, a);
        acc = w_tile<2, 64>(a, lW2T, wv, col, quad, init);
    }
    __syncthreads();
    w_store1(SL, wv, col, quad, acc, false);
    __syncthreads();

    a_load<2>(SL, col, quad, a);
    acc = w_tile<2, 64>(a, gW1T, wv, col, quad, mk4(gb1[wv * 16 + col]));
    __syncthreads();
    w_store1(SL, wv, col, quad, acc, true);
    __syncthreads();

    a_load<2>(SL, col, quad, a);
    acc = w_tile<2, 64>(a, gW2T, wv, col, quad, mk4(gb2[wv * 16 + col]));
    __syncthreads();
    w_store1(SL, wv, col, quad, acc, true);
    __syncthreads();

    a_load<2>(SL, col, quad, a);
    acc = w_tile<2, 64>(a, aTn, wv, col, quad, mk4(0.f));
    g_store1(u, gn0, wv, col, quad, acc);

    const float* W1c = lW1f_next + 128 * 64;
    int ch = wv * 16 + col;
    acc = w_tile<2, 64>(a, bTn, wv, col, quad, mk4(b1n[ch]));
    float w0 = W1c[ch], w1 = W1c[64 + ch], w2 = W1c[128 + ch];
#pragma unroll
    for (int r = 0; r < 4; ++r) {
        int rr = quad * 4 + r;
        acc[r] += pw[rr * 3 + 0] * w0 + pw[rr * 3 + 1] * w1 + pw[rr * 3 + 2] * w2;
    }
    g_store1(vout, gn0, wv, col, quad, acc);
}

// ---------------------------------------------------------------------------
// kC (layer 2): fused aggregation + 4-wave N-split chain + readout bins
// ---------------------------------------------------------------------------
__global__ __launch_bounds__(256) void kC(
    const int* __restrict__ rowPtr, const unsigned short* __restrict__ srcList,
    const int* __restrict__ batch, const unsigned short* __restrict__ WT,
    const float* __restrict__ lb2, const float* __restrict__ gb1,
    const float* __restrict__ gb2,
    const float* __restrict__ lin1b, const float* __restrict__ lin2b,
    unsigned short* __restrict__ u, const unsigned short* __restrict__ vin,
    float* __restrict__ out) {
    __shared__ unsigned short SL[16 * XPITCH];
    __shared__ int rp[17];
    __shared__ int batchW[16];
    __shared__ float bins[16 * 8];
    int tid = threadIdx.x;
    int lane = tid & 63;
    int wv = __builtin_amdgcn_readfirstlane(tid >> 6);
    int gn0 = blockIdx.x * 16;   // N_NODES % 16 == 0
    int col = lane & 15, quad = lane >> 4;

    const unsigned short* LYR = WT + OFF_LYR + 2 * LYR_SZ;
    const unsigned short* lW2T = LYR + 2 * 4096;
    const unsigned short* gW1T = LYR + 3 * 4096;
    const unsigned short* gW2T = LYR + 4 * 4096;
    const unsigned short* lin1T = WT + OFF_LIN1T;
    const unsigned short* lin2T = WT + OFF_LIN2T;

    if (tid < 17) rp[tid] = rowPtr[gn0 + tid];
    if (tid < 16) batchW[tid] = batch[gn0 + tid];
    if (tid >= 128 && tid < 256) bins[tid - 128] = 0.f;
    __syncthreads();

    wave_agg4(rp, SL, u, vin, srcList, gn0, wv, lane);
    __syncthreads();

    bf16x8 a[2];
    f32x4 acc;
    float dgr[4];
#pragma unroll
    for (int r = 0; r < 4; ++r)
        dgr[r] = (float)(rp[quad * 4 + r + 1] - rp[quad * 4 + r]);

    {
        float b = lb2[wv * 16 + col];
        f32x4 init = {dgr[0] * b, dgr[1] * b, dgr[2] * b, dgr[3] * b};
        a_load<2>(SL, col, quad, a);
        acc = w_tile<2, 64>(a, lW2T, wv, col, quad, init);
    }
    __syncthreads();
    w_store1(SL, wv, col, quad, acc, false);
    __syncthreads();

    a_load<2>(SL, col, quad, a);
    acc = w_tile<2, 64>(a, gW1T, wv, col, quad, mk4(gb1[wv * 16 + col]));
    __syncthreads();
    w_store1(SL, wv, col, quad, acc, true);
    __syncthreads();

    a_load<2>(SL, col, quad, a);
    acc = w_tile<2, 64>(a, gW2T, wv, col, quad, mk4(gb2[wv * 16 + col]));
    __syncthreads();
    w_store1(SL, wv, col, quad, acc, true);
    __syncthreads();

    // lin1: 32 output cols -> waves 0,1 only
    a_load<2>(SL, col, quad, a);
    if (wv < 2)
        acc = w_tile<2, 64>(a, lin1T, wv, col, quad, mk4(lin1b[wv * 16 + col]));
    __syncthreads();
    if (wv < 2) w_store1(SL, wv, col, quad, acc, true);
    __syncthreads();

    // lin2: 8 output cols -> wave 0 only; accumulate into per-block bins
    if (wv == 0) {
        a_load<1>(SL, col, quad, a);
        f32x4 o = w_tile<1, 32>(a, lin2T, 0, col, quad,
                                mk4(col < 8 ? lin2b[col] : 0.f));
        int gmin = batchW[0];
        if (col < 8) {
#pragma unroll
            for (int r = 0; r < 4; ++r) {
                int nl = quad * 4 + r;
                atomicAdd(&bins[(batchW[nl] - gmin) * 8 + col], o[r]);
            }
        }
    }
    __syncthreads();
    int gmin = batchW[0];
    int nb8 = (batchW[15] - gmin + 1) * 8;
    for (int idx = tid; idx < nb8; idx += 256)
        atomAddF(&out[gmin * 8 + idx], bins[idx]);
}

// ---------------------------------------------------------------------------
// launch
// ---------------------------------------------------------------------------
extern "C" void kernel_launch(void* const* d_in, const int* in_sizes, int n_in,
                              void* d_out, int out_size, void* d_ws, size_t ws_size,
                              hipStream_t stream) {
    const float* x     = (const float*)d_in[0];
    const float* pos   = (const float*)d_in[1];
    const int*   ei    = (const int*)d_in[2];
    const int*   batch = (const int*)d_in[3];
    const float* nW1   = (const float*)d_in[4];
    const float* nb1   = (const float*)d_in[5];
    const float* nW2   = (const float*)d_in[6];
    const float* nb2   = (const float*)d_in[7];
    const float* lW1   = (const float*)d_in[8];
    const float* lb1   = (const float*)d_in[9];
    const float* lW2   = (const float*)d_in[10];
    const float* lb2   = (const float*)d_in[11];
    const float* gW1   = (const float*)d_in[12];
    const float* gb1   = (const float*)d_in[13];
    const float* gW2   = (const float*)d_in[14];
    const float* gb2   = (const float*)d_in[15];
    const float* lin1W = (const float*)d_in[16];
    const float* lin1b = (const float*)d_in[17];
    const float* lin2W = (const float*)d_in[18];
    const float* lin2b = (const float*)d_in[19];
    float* out = (float*)d_out;

    // workspace: u in-place; v ping-pong (v0/v1)
    unsigned short* u  = (unsigned short*)d_ws;          // N*64 bf16
    unsigned short* v0 = u + (size_t)N_NODES * 64;       // N*64 bf16
    unsigned short* v1 = v0 + (size_t)N_NODES * 64;      // N*64 bf16
    unsigned short* WT = v1 + (size_t)N_NODES * 64;      // WT_TOTAL bf16
    int* gHist = (int*)(WT + WT_TOTAL);                  // NB
    int* bucketOff = gHist + NB;                         // NB+1
    int* cursor = bucketOff + NB + 1;                    // NB
    int* rowPtr = cursor + NB;                           // N+1
    int* doneCnt = rowPtr + N_NODES + 1;                 // 1
    int* packs = doneCnt + 1;                            // E int
    unsigned short* srcList = (unsigned short*)(packs + N_EDGES); // E ushort

    kPrep<<<(WT_TOTAL + 255) / 256, 256, 0, stream>>>(nW1, nW2, lW1, lW2, gW1, gW2,
                                                      lin1W, lin2W, WT, gHist,
                                                      doneCnt, out);
    kHist<<<(N_EDGES + HEPB - 1) / HEPB, 256, 0, stream>>>(ei, gHist, bucketOff,
                                                           cursor, doneCnt);
    kScat<<<(N_EDGES + SEPB - 1) / SEPB, 256, 0, stream>>>(ei, cursor, packs);
    kSortA<<<NB + NGRP, 256, 0, stream>>>(bucketOff, packs, srcList, rowPtr,
                                          x, pos, WT, nb1, nb2, lW1, lb1, u, v0);

    kB<<<NGRP, 256, 0, stream>>>(
        pos, rowPtr, srcList, WT, 0,
        lb2 + 0, gb1 + 0, gb2 + 0,
        lW1 + (size_t)1 * 131 * 64, lb1 + 64,
        u, v0, v1);
    kB<<<NGRP, 256, 0, stream>>>(
        pos, rowPtr, srcList, WT, 1,
        lb2 + 64, gb1 + 64, gb2 + 64,
        lW1 + (size_t)2 * 131 * 64, lb1 + 128,
        u, v1, v0);
    kC<<<NGRP, 256, 0, stream>>>(
        rowPtr, srcList, batch, WT,
        lb2 + 128, gb1 + 128, gb2 + 128, lin1b, lin2b,
        u, v0, out);
}

// Round 6
// 257.218 us; speedup vs baseline: 1.3707x; 1.0743x over previous
//
#include <hip/hip_runtime.h>

#define N_NODES 50000
#define N_EDGES 800000
#define NGRAPH  128
#define XPITCH  72   // ushort pitch: 72*2=144B, 16B-aligned rows, 2-way (free) banks
#define NB      391  // dst buckets of 128 nodes
#define HEPB    4096
#define SEPB    8192
#define NGRP    3125 // 16-node groups (50000/16 exact)
#define STRIDE  64   // per-node srcList slots (max Poisson(16) deg << 64)
#define SENT    N_NODES  // sentinel src -> v row N_NODES = -inf => relu contribution 0

typedef short bf16x8 __attribute__((ext_vector_type(8)));
typedef float f32x4  __attribute__((ext_vector_type(4)));

// ---------------------------------------------------------------------------
// helpers
// ---------------------------------------------------------------------------

__device__ __forceinline__ float atomAddF(float* p, float v) {
#if defined(__gfx950__) || defined(__AMDGCN__)
    return unsafeAtomicAdd(p, v);
#else
    return atomicAdd(p, v);
#endif
}

__device__ __forceinline__ unsigned short f2bf(float x) {  // RNE f32 -> bf16
    unsigned u = __builtin_bit_cast(unsigned, x);
    u += 0x7fffu + ((u >> 16) & 1u);
    return (unsigned short)(u >> 16);
}
__device__ __forceinline__ float bf2f(unsigned short h) {
    return __builtin_bit_cast(float, (unsigned)h << 16);
}

__device__ __forceinline__ f32x4 mk4(float b) { f32x4 a = {b, b, b, b}; return a; }

// One 16x16 tile vs weight mat, A-frags preloaded in regs.
template<int NKC, int KROW>
__device__ __forceinline__ f32x4 w_tile(const bf16x8* a,
                                        const unsigned short* __restrict__ Wm,
                                        int nt, int col, int quad, f32x4 acc) {
    const unsigned short* wp = Wm + (nt * 16 + col) * KROW + quad * 8;
#pragma unroll
    for (int c = 0; c < NKC; ++c) {
        bf16x8 b = *(const bf16x8*)(wp + c * 32);
        acc = __builtin_amdgcn_mfma_f32_16x16x32_bf16(a[c], b, acc, 0, 0, 0);
    }
    return acc;
}

// load A-frags from the block-shared 16-node slice
template<int NKC>
__device__ __forceinline__ void a_load(const unsigned short* __restrict__ sl,
                                       int col, int quad, bf16x8* a) {
    a[0] = *(const bf16x8*)(sl + col * XPITCH + quad * 8);
    if (NKC > 1) a[1] = *(const bf16x8*)(sl + col * XPITCH + quad * 8 + 32);
}

// write this wave's 16-col tile back into the shared slice
__device__ __forceinline__ void w_store1(unsigned short* __restrict__ sl,
                                         int wv, int col, int quad, f32x4 acc,
                                         bool relu) {
#pragma unroll
    for (int r = 0; r < 4; ++r) {
        float x = acc[r];
        if (relu) x = fmaxf(x, 0.f);
        sl[(quad * 4 + r) * XPITCH + wv * 16 + col] = f2bf(x);
    }
}

// store this wave's 16-col tile to global rows (node-major bf16[64])
__device__ __forceinline__ void g_store1(unsigned short* __restrict__ g, int gn0,
                                         int wv, int col, int quad, f32x4 acc) {
#pragma unroll
    for (int r = 0; r < 4; ++r) {
        int node = gn0 + quad * 4 + r;
        if (node < N_NODES)
            g[(size_t)node * 64 + wv * 16 + col] = f2bf(acc[r]);
    }
}

// ---------------------------------------------------------------------------
// per-wave fused aggregation over sentinel-padded fixed-stride CSR.
// Wave handles nodes gn0+4*wv .. +3. All edges go through the batched
// 16-edges-per-iter path (pad slots hold SENT -> v row = -inf -> relu = 0).
// No tail loop, no per-edge dependent chain beyond srcList->gather.
// ---------------------------------------------------------------------------
__device__ __forceinline__ void wave_agg4(const int* dg, unsigned short* __restrict__ sl,
                                          const unsigned short* __restrict__ u,
                                          const unsigned short* __restrict__ vin,
                                          const unsigned short* __restrict__ srcList,
                                          int gn0, int wv, int lane) {
    int sub = lane & 15, q = lane >> 4;
    int n0 = gn0 + wv * 4;
    ushort4 uu4[4];
#pragma unroll
    for (int mi = 0; mi < 4; ++mi)
        uu4[mi] = *(const ushort4*)(u + (size_t)(n0 + mi) * 64 + sub * 4);

#pragma unroll
    for (int mi = 0; mi < 4; ++mi) {
        int m = wv * 4 + mi;
        float u0 = bf2f(uu4[mi].x), u1 = bf2f(uu4[mi].y);
        float u2 = bf2f(uu4[mi].z), u3 = bf2f(uu4[mi].w);
        int pdeg = (dg[m] + 15) & ~15;
        size_t b = (size_t)(n0 + mi) * STRIDE;
        float a0 = 0.f, a1 = 0.f, a2 = 0.f, a3 = 0.f;

        for (int g0 = 0; g0 < pdeg; g0 += 16) {
            ushort4 ss = *(const ushort4*)(srcList + b + g0 + 4 * q);  // 8B aligned
            int s0 = ss.x, s1 = ss.y, s2 = ss.z, s3 = ss.w;
            ushort4 w0 = *(const ushort4*)(vin + (size_t)s0 * 64 + sub * 4);
            ushort4 w1 = *(const ushort4*)(vin + (size_t)s1 * 64 + sub * 4);
            ushort4 w2 = *(const ushort4*)(vin + (size_t)s2 * 64 + sub * 4);
            ushort4 w3 = *(const ushort4*)(vin + (size_t)s3 * 64 + sub * 4);
            a0 += fmaxf(u0 + bf2f(w0.x), 0.f) + fmaxf(u0 + bf2f(w1.x), 0.f)
                + fmaxf(u0 + bf2f(w2.x), 0.f) + fmaxf(u0 + bf2f(w3.x), 0.f);
            a1 += fmaxf(u1 + bf2f(w0.y), 0.f) + fmaxf(u1 + bf2f(w1.y), 0.f)
                + fmaxf(u1 + bf2f(w2.y), 0.f) + fmaxf(u1 + bf2f(w3.y), 0.f);
            a2 += fmaxf(u2 + bf2f(w0.z), 0.f) + fmaxf(u2 + bf2f(w1.z), 0.f)
                + fmaxf(u2 + bf2f(w2.z), 0.f) + fmaxf(u2 + bf2f(w3.z), 0.f);
            a3 += fmaxf(u3 + bf2f(w0.w), 0.f) + fmaxf(u3 + bf2f(w1.w), 0.f)
                + fmaxf(u3 + bf2f(w2.w), 0.f) + fmaxf(u3 + bf2f(w3.w), 0.f);
        }

        a0 += __shfl_xor(a0, 16); a0 += __shfl_xor(a0, 32);
        a1 += __shfl_xor(a1, 16); a1 += __shfl_xor(a1, 32);
        a2 += __shfl_xor(a2, 16); a2 += __shfl_xor(a2, 32);
        a3 += __shfl_xor(a3, 16); a3 += __shfl_xor(a3, 32);

        if (q == 0) {
            ushort4 o;
            o.x = f2bf(a0); o.y = f2bf(a1); o.z = f2bf(a2); o.w = f2bf(a3);
            *(ushort4*)&sl[m * XPITCH + sub * 4] = o;
        }
    }
}

// ---------------------------------------------------------------------------
// weight prep (transpose + bf16 into B-operand layout); zeroes counters/out;
// writes the -inf sentinel row (row N_NODES) of v0/v1.
// ---------------------------------------------------------------------------
#define OFF_NW1T  0
#define OFF_NW2T  2048
#define OFF_LYR   6144
#define LYR_SZ    20480
#define OFF_LIN1T 67584
#define OFF_LIN2T 69632
#define WT_TOTAL  70144

__global__ __launch_bounds__(256) void kPrep(
    const float* __restrict__ nW1, const float* __restrict__ nW2,
    const float* __restrict__ lW1, const float* __restrict__ lW2,
    const float* __restrict__ gW1, const float* __restrict__ gW2,
    const float* __restrict__ lin1W, const float* __restrict__ lin2W,
    unsigned short* __restrict__ WT, int* __restrict__ gHist,
    int* __restrict__ doneCnt, float* __restrict__ out,
    unsigned short* __restrict__ v0, unsigned short* __restrict__ v1) {
    int i = blockIdx.x * 256 + threadIdx.x;
    if (blockIdx.x == 0) {
        for (int k = threadIdx.x; k < NB; k += 256) gHist[k] = 0;
        for (int k = threadIdx.x; k < NGRAPH * 8; k += 256) out[k] = 0.f;
        if (threadIdx.x == 0) *doneCnt = 0;
    }
    if (i < 64) {  // sentinel row = -inf (bf16 0xFF80)
        v0[(size_t)N_NODES * 64 + i] = 0xFF80;
        v1[(size_t)N_NODES * 64 + i] = 0xFF80;
    }
    if (i >= WT_TOTAL) return;
    int j = i;
    if (j < 2048) {
        int n = j >> 5, k = j & 31;
        WT[i] = (k < 16) ? f2bf(nW1[k * 64 + n]) : 0;
        return;
    }
    j -= 2048;
    if (j < 4096) {
        int n = j >> 6, k = j & 63;
        WT[i] = f2bf(nW2[k * 64 + n]);
        return;
    }
    j -= 4096;
    if (j < 3 * LYR_SZ) {
        int l = j / LYR_SZ;  j -= l * LYR_SZ;
        int m = j >> 12;     j &= 4095;
        int n = j >> 6, k = j & 63;
        const float* src;
        if (m == 0)      src = lW1 + (size_t)l * 131 * 64;
        else if (m == 1) src = lW1 + (size_t)l * 131 * 64 + 64 * 64;
        else if (m == 2) src = lW2 + (size_t)l * 4096;
        else if (m == 3) src = gW1 + (size_t)l * 4096;
        else             src = gW2 + (size_t)l * 4096;
        WT[i] = f2bf(src[k * 64 + n]);
        return;
    }
    j -= 3 * LYR_SZ;
    if (j < 2048) {
        int n = j >> 6, k = j & 63;
        WT[i] = f2bf(lin1W[k * 32 + n]);
        return;
    }
    j -= 2048;
    {
        int n = j >> 5, k = j & 31;
        WT[i] = (n < 8) ? f2bf(lin2W[k * 8 + n]) : 0;
    }
}

// ---------------------------------------------------------------------------
// kHist: LDS bucket hist -> gHist atomics. LAST block (threadfence + done-
// counter) scans the 391 buckets, writing bucketOff + cursor in-kernel.
// ---------------------------------------------------------------------------
__global__ __launch_bounds__(256) void kHist(const int* __restrict__ ei,
                                             int* __restrict__ gHist,
                                             int* __restrict__ bucketOff,
                                             int* __restrict__ cursor,
                                             int* __restrict__ doneCnt) {
    __shared__ int h[NB];
    __shared__ int s0[512], s1[512];
    __shared__ int amLast;
    int tid = threadIdx.x;
    for (int i = tid; i < NB; i += 256) h[i] = 0;
    __syncthreads();
    int base = blockIdx.x * HEPB;
#pragma unroll
    for (int k = 0; k < HEPB; k += 256) {
        int e = base + k + tid;
        if (e < N_EDGES) atomicAdd(&h[ei[N_EDGES + e] >> 7], 1);
    }
    __syncthreads();
    for (int i = tid; i < NB; i += 256)
        if (h[i]) atomicAdd(&gHist[i], h[i]);

    __threadfence();
    if (tid == 0) amLast = (atomicAdd(doneCnt, 1) == (int)gridDim.x - 1);
    __syncthreads();
    if (!amLast) return;
    __threadfence();

    for (int e = tid; e < 512; e += 256)
        s0[e] = (e < NB) ? atomicAdd(&gHist[e], 0) : 0;  // coherent read
    __syncthreads();
    int* sp = s0; int* dp = s1;
    for (int off = 1; off < 512; off <<= 1) {
        for (int e = tid; e < 512; e += 256)
            dp[e] = sp[e] + ((e >= off) ? sp[e - off] : 0);
        __syncthreads();
        int* t = sp; sp = dp; dp = t;
    }
    for (int e = tid; e < NB; e += 256) {
        int cnt = atomicAdd(&gHist[e], 0);
        int excl = sp[e] - cnt;
        bucketOff[e] = excl;
        cursor[e] = excl;
    }
    if (tid == 0) bucketOff[NB] = sp[NB - 1];
}

__global__ __launch_bounds__(256) void kScat(const int* __restrict__ ei,
                                             int* __restrict__ cursor,
                                             int* __restrict__ packs) {
    __shared__ int sdata[SEPB];
    __shared__ int hist[NB];
    __shared__ int loff[NB + 1];
    __shared__ int gbase[NB];
    __shared__ int sc0[512], sc1[512];
    int tid = threadIdx.x;
    int base = blockIdx.x * SEPB;
    int nE = min(SEPB, N_EDGES - base);

    for (int i = tid; i < NB; i += 256) hist[i] = 0;
    __syncthreads();

    int myPack[SEPB / 256];
    unsigned short myRank[SEPB / 256];
#pragma unroll
    for (int kk = 0; kk < SEPB / 256; ++kk) {
        int e = base + kk * 256 + tid;
        if (e < N_EDGES) {
            int s = ei[e], d = ei[N_EDGES + e];
            myPack[kk] = (s << 16) | d;
            myRank[kk] = (unsigned short)atomicAdd(&hist[d >> 7], 1);
        }
    }
    __syncthreads();

    for (int e = tid; e < 512; e += 256) sc0[e] = (e < NB) ? hist[e] : 0;
    __syncthreads();
    int* sp = sc0; int* dp = sc1;
    for (int off = 1; off < 512; off <<= 1) {
        for (int e = tid; e < 512; e += 256)
            dp[e] = sp[e] + ((e >= off) ? sp[e - off] : 0);
        __syncthreads();
        int* t = sp; sp = dp; dp = t;
    }
    for (int e = tid; e < NB; e += 256) loff[e] = sp[e] - hist[e];
    if (tid == 0) loff[NB] = sp[NB - 1];
    __syncthreads();

    for (int e = tid; e < NB; e += 256)
        gbase[e] = hist[e] ? atomicAdd(&cursor[e], hist[e]) : 0;
#pragma unroll
    for (int kk = 0; kk < SEPB / 256; ++kk) {
        int e = base + kk * 256 + tid;
        if (e < N_EDGES) {
            int p = myPack[kk];
            int b = (p & 0xffff) >> 7;
            sdata[loff[b] + myRank[kk]] = p;
        }
    }
    __syncthreads();

    for (int i = tid; i < nE; i += 256) {
        int p = sdata[i];
        int b = (p & 0xffff) >> 7;
        packs[gbase[b] + (i - loff[b])] = p;
    }
}

// ---------------------------------------------------------------------------
// kSortA: merged dispatch. Blocks [0,NB): ONE-PASS rank scatter into the
// fixed-stride srcList (cur[] LDS atomics), deg write, sentinel pad fill.
// Blocks [NB, NB+NGRP): kA node pipelines (4 waves N-split).
// ---------------------------------------------------------------------------
__global__ __launch_bounds__(256) void kSortA(
    const int* __restrict__ bucketOff, const int* __restrict__ packs,
    unsigned short* __restrict__ srcList, int* __restrict__ degArr,
    const float* __restrict__ x, const float* __restrict__ pos,
    const unsigned short* __restrict__ WT,
    const float* __restrict__ nb1, const float* __restrict__ nb2,
    const float* __restrict__ lW1f, const float* __restrict__ lb1,
    unsigned short* __restrict__ u, unsigned short* __restrict__ v) {
    __shared__ int cur[128];
    __shared__ unsigned short SL[16 * XPITCH];
    __shared__ float pw[48];

    int tid = threadIdx.x;
    if (blockIdx.x < NB) {
        int nbk = blockIdx.x;
        int nodeBase = nbk * 128;
        int nvalid = min(128, N_NODES - nodeBase);
        int eb = bucketOff[nbk], ee = bucketOff[nbk + 1];

        if (tid < 128) cur[tid] = 0;
        __syncthreads();
        for (int i = eb + tid; i < ee; i += 256) {
            int p = packs[i];
            int node = p & 127;
            int r = atomicAdd(&cur[node], 1);
            if (r < STRIDE)
                srcList[(size_t)(nodeBase + node) * STRIDE + r] =
                    (unsigned short)(((unsigned)p) >> 16);
        }
        __syncthreads();
        if (tid < nvalid) {
            int d = min(cur[tid], STRIDE);
            degArr[nodeBase + tid] = d;
            int pd = (d + 15) & ~15;
            size_t b2 = (size_t)(nodeBase + tid) * STRIDE;
            for (int r = d; r < pd; ++r) srcList[b2 + r] = (unsigned short)SENT;
        }
        return;
    }

    // ---- kA body: one 16-node group, 4 waves N-split ----
    int gn0 = (blockIdx.x - NB) * 16;
    int lane = tid & 63;
    int wv = __builtin_amdgcn_readfirstlane(tid >> 6);
    int col = lane & 15, quad = lane >> 4;

    for (int idx = tid; idx < 512; idx += 256) {
        int m = idx >> 5, k = idx & 31;
        int node = gn0 + m;
        float val = (k < 16) ? x[(size_t)node * 16 + k] : 0.f;
        SL[m * XPITCH + k] = f2bf(val);
    }
    if (tid < 48) {
        int node = gn0 + tid / 3;
        pw[tid] = pos[(size_t)node * 3 + tid % 3];
    }
    __syncthreads();

    bf16x8 a[2];
    f32x4 acc;

    a_load<1>(SL, col, quad, a);
    acc = w_tile<1, 32>(a, WT + OFF_NW1T, wv, col, quad, mk4(nb1[wv * 16 + col]));
    __syncthreads();
    w_store1(SL, wv, col, quad, acc, true);
    __syncthreads();

    a_load<2>(SL, col, quad, a);
    acc = w_tile<2, 64>(a, WT + OFF_NW2T, wv, col, quad, mk4(nb2[wv * 16 + col]));
    __syncthreads();
    w_store1(SL, wv, col, quad, acc, false);
    __syncthreads();

    const unsigned short* aT = WT + OFF_LYR;
    const unsigned short* bT = aT + 4096;
    const float* W1c = lW1f + 128 * 64;

    a_load<2>(SL, col, quad, a);
    acc = w_tile<2, 64>(a, aT, wv, col, quad, mk4(0.f));
    g_store1(u, gn0, wv, col, quad, acc);

    int ch = wv * 16 + col;
    acc = w_tile<2, 64>(a, bT, wv, col, quad, mk4(lb1[ch]));
    float w0 = W1c[ch], w1 = W1c[64 + ch], w2 = W1c[128 + ch];
#pragma unroll
    for (int r = 0; r < 4; ++r) {
        int rr = quad * 4 + r;
        acc[r] += pw[rr * 3 + 0] * w0 + pw[rr * 3 + 1] * w1 + pw[rr * 3 + 2] * w2;
    }
    g_store1(v, gn0, wv, col, quad, acc);
}

// ---------------------------------------------------------------------------
// kB (layers 0,1): fused agg (sentinel-padded CSR) + 4-wave N-split GEMM
// chain. u in-place; v ping-pong.
// ---------------------------------------------------------------------------
__global__ __launch_bounds__(256) void kB(
    const float* __restrict__ pos, const int* __restrict__ degArr,
    const unsigned short* __restrict__ srcList,
    const unsigned short* __restrict__ WT, int l,
    const float* __restrict__ lb2, const float* __restrict__ gb1,
    const float* __restrict__ gb2,
    const float* __restrict__ lW1f_next, const float* __restrict__ b1n,
    unsigned short* __restrict__ u,
    const unsigned short* __restrict__ vin,
    unsigned short* __restrict__ vout) {
    __shared__ unsigned short SL[16 * XPITCH];
    __shared__ float pw[48];
    __shared__ int dgW[16];
    int tid = threadIdx.x;
    int lane = tid & 63;
    int wv = __builtin_amdgcn_readfirstlane(tid >> 6);
    int gn0 = blockIdx.x * 16;   // N_NODES % 16 == 0
    int col = lane & 15, quad = lane >> 4;

    const unsigned short* LYR = WT + OFF_LYR + (size_t)l * LYR_SZ;
    const unsigned short* lW2T = LYR + 2 * 4096;
    const unsigned short* gW1T = LYR + 3 * 4096;
    const unsigned short* gW2T = LYR + 4 * 4096;
    const unsigned short* aTn = WT + OFF_LYR + (size_t)(l + 1) * LYR_SZ;
    const unsigned short* bTn = aTn + 4096;

    if (tid < 48) {
        int node = gn0 + tid / 3;
        pw[tid] = pos[(size_t)node * 3 + tid % 3];
    }
    if (tid < 16) dgW[tid] = degArr[gn0 + tid];
    __syncthreads();

    wave_agg4(dgW, SL, u, vin, srcList, gn0, wv, lane);
    __syncthreads();

    bf16x8 a[2];
    f32x4 acc;
    float dgr[4];
#pragma unroll
    for (int r = 0; r < 4; ++r) dgr[r] = (float)dgW[quad * 4 + r];

    {
        float b = lb2[wv * 16 + col];
        f32x4 init = {dgr[0] * b, dgr[1] * b, dgr[2] * b, dgr[3] * b};
        a_load<2>(SL, col, quad, a);
        acc = w_tile<2, 64>(a, lW2T, wv, col, quad, init);
    }
    __syncthreads();
    w_store1(SL, wv, col, quad, acc, false);
    __syncthreads();

    a_load<2>(SL, col, quad, a);
    acc = w_tile<2, 64>(a, gW1T, wv, col, quad, mk4(gb1[wv * 16 + col]));
    __syncthreads();
    w_store1(SL, wv, col, quad, acc, true);
    __syncthreads();

    a_load<2>(SL, col, quad, a);
    acc = w_tile<2, 64>(a, gW2T, wv, col, quad, mk4(gb2[wv * 16 + col]));
    __syncthreads();
    w_store1(SL, wv, col, quad, acc, true);
    __syncthreads();

    a_load<2>(SL, col, quad, a);
    acc = w_tile<2, 64>(a, aTn, wv, col, quad, mk4(0.f));
    g_store1(u, gn0, wv, col, quad, acc);

    const float* W1c = lW1f_next + 128 * 64;
    int ch = wv * 16 + col;
    acc = w_tile<2, 64>(a, bTn, wv, col, quad, mk4(b1n[ch]));
    float w0 = W1c[ch], w1 = W1c[64 + ch], w2 = W1c[128 + ch];
#pragma unroll
    for (int r = 0; r < 4; ++r) {
        int rr = quad * 4 + r;
        acc[r] += pw[rr * 3 + 0] * w0 + pw[rr * 3 + 1] * w1 + pw[rr * 3 + 2] * w2;
    }
    g_store1(vout, gn0, wv, col, quad, acc);
}

// ---------------------------------------------------------------------------
// kC (layer 2): fused agg + 4-wave N-split chain + readout bins
// ---------------------------------------------------------------------------
__global__ __launch_bounds__(256) void kC(
    const int* __restrict__ degArr, const unsigned short* __restrict__ srcList,
    const int* __restrict__ batch, const unsigned short* __restrict__ WT,
    const float* __restrict__ lb2, const float* __restrict__ gb1,
    const float* __restrict__ gb2,
    const float* __restrict__ lin1b, const float* __restrict__ lin2b,
    const unsigned short* __restrict__ u, const unsigned short* __restrict__ vin,
    float* __restrict__ out) {
    __shared__ unsigned short SL[16 * XPITCH];
    __shared__ int dgW[16];
    __shared__ int batchW[16];
    __shared__ float bins[16 * 8];
    int tid = threadIdx.x;
    int lane = tid & 63;
    int wv = __builtin_amdgcn_readfirstlane(tid >> 6);
    int gn0 = blockIdx.x * 16;   // N_NODES % 16 == 0
    int col = lane & 15, quad = lane >> 4;

    const unsigned short* LYR = WT + OFF_LYR + 2 * LYR_SZ;
    const unsigned short* lW2T = LYR + 2 * 4096;
    const unsigned short* gW1T = LYR + 3 * 4096;
    const unsigned short* gW2T = LYR + 4 * 4096;
    const unsigned short* lin1T = WT + OFF_LIN1T;
    const unsigned short* lin2T = WT + OFF_LIN2T;

    if (tid < 16) dgW[tid] = degArr[gn0 + tid];
    if (tid >= 32 && tid < 48) batchW[tid - 32] = batch[gn0 + tid - 32];
    if (tid >= 128 && tid < 256) bins[tid - 128] = 0.f;
    __syncthreads();

    wave_agg4(dgW, SL, u, vin, srcList, gn0, wv, lane);
    __syncthreads();

    bf16x8 a[2];
    f32x4 acc;
    float dgr[4];
#pragma unroll
    for (int r = 0; r < 4; ++r) dgr[r] = (float)dgW[quad * 4 + r];

    {
        float b = lb2[wv * 16 + col];
        f32x4 init = {dgr[0] * b, dgr[1] * b, dgr[2] * b, dgr[3] * b};
        a_load<2>(SL, col, quad, a);
        acc = w_tile<2, 64>(a, lW2T, wv, col, quad, init);
    }
    __syncthreads();
    w_store1(SL, wv, col, quad, acc, false);
    __syncthreads();

    a_load<2>(SL, col, quad, a);
    acc = w_tile<2, 64>(a, gW1T, wv, col, quad, mk4(gb1[wv * 16 + col]));
    __syncthreads();
    w_store1(SL, wv, col, quad, acc, true);
    __syncthreads();

    a_load<2>(SL, col, quad, a);
    acc = w_tile<2, 64>(a, gW2T, wv, col, quad, mk4(gb2[wv * 16 + col]));
    __syncthreads();
    w_store1(SL, wv, col, quad, acc, true);
    __syncthreads();

    // lin1: 32 output cols -> waves 0,1 only
    a_load<2>(SL, col, quad, a);
    if (wv < 2)
        acc = w_tile<2, 64>(a, lin1T, wv, col, quad, mk4(lin1b[wv * 16 + col]));
    __syncthreads();
    if (wv < 2) w_store1(SL, wv, col, quad, acc, true);
    __syncthreads();

    // lin2: 8 output cols -> wave 0 only; accumulate into per-block bins
    if (wv == 0) {
        a_load<1>(SL, col, quad, a);
        f32x4 o = w_tile<1, 32>(a, lin2T, 0, col, quad,
                                mk4(col < 8 ? lin2b[col] : 0.f));
        int gmin = batchW[0];
        if (col < 8) {
#pragma unroll
            for (int r = 0; r < 4; ++r) {
                int nl = quad * 4 + r;
                atomicAdd(&bins[(batchW[nl] - gmin) * 8 + col], o[r]);
            }
        }
    }
    __syncthreads();
    int gmin = batchW[0];
    int nb8 = (batchW[15] - gmin + 1) * 8;
    for (int idx = tid; idx < nb8; idx += 256)
        atomAddF(&out[gmin * 8 + idx], bins[idx]);
}

// ---------------------------------------------------------------------------
// launch
// ---------------------------------------------------------------------------
extern "C" void kernel_launch(void* const* d_in, const int* in_sizes, int n_in,
                              void* d_out, int out_size, void* d_ws, size_t ws_size,
                              hipStream_t stream) {
    const float* x     = (const float*)d_in[0];
    const float* pos   = (const float*)d_in[1];
    const int*   ei    = (const int*)d_in[2];
    const int*   batch = (const int*)d_in[3];
    const float* nW1   = (const float*)d_in[4];
    const float* nb1   = (const float*)d_in[5];
    const float* nW2   = (const float*)d_in[6];
    const float* nb2   = (const float*)d_in[7];
    const float* lW1   = (const float*)d_in[8];
    const float* lb1   = (const float*)d_in[9];
    const float* lW2   = (const float*)d_in[10];
    const float* lb2   = (const float*)d_in[11];
    const float* gW1   = (const float*)d_in[12];
    const float* gb1   = (const float*)d_in[13];
    const float* gW2   = (const float*)d_in[14];
    const float* gb2   = (const float*)d_in[15];
    const float* lin1W = (const float*)d_in[16];
    const float* lin1b = (const float*)d_in[17];
    const float* lin2W = (const float*)d_in[18];
    const float* lin2b = (const float*)d_in[19];
    float* out = (float*)d_out;

    // workspace: u N rows; v0/v1 N+1 rows (row N = -inf sentinel)
    unsigned short* u  = (unsigned short*)d_ws;              // N*64 bf16
    unsigned short* v0 = u + (size_t)N_NODES * 64;           // (N+1)*64 bf16
    unsigned short* v1 = v0 + (size_t)(N_NODES + 1) * 64;    // (N+1)*64 bf16
    unsigned short* WT = v1 + (size_t)(N_NODES + 1) * 64;    // WT_TOTAL bf16
    int* gHist = (int*)(WT + WT_TOTAL);                      // NB
    int* bucketOff = gHist + NB;                             // NB+1
    int* cursor = bucketOff + NB + 1;                        // NB
    int* doneCnt = cursor + NB;                              // 1
    int* degArr = doneCnt + 1;                               // N
    int* packs = degArr + N_NODES;                           // E int
    unsigned short* srcList = (unsigned short*)(packs + N_EDGES); // N*STRIDE ushort

    kPrep<<<(WT_TOTAL + 255) / 256, 256, 0, stream>>>(nW1, nW2, lW1, lW2, gW1, gW2,
                                                      lin1W, lin2W, WT, gHist,
                                                      doneCnt, out, v0, v1);
    kHist<<<(N_EDGES + HEPB - 1) / HEPB, 256, 0, stream>>>(ei, gHist, bucketOff,
                                                           cursor, doneCnt);
    kScat<<<(N_EDGES + SEPB - 1) / SEPB, 256, 0, stream>>>(ei, cursor, packs);
    kSortA<<<NB + NGRP, 256, 0, stream>>>(bucketOff, packs, srcList, degArr,
                                          x, pos, WT, nb1, nb2, lW1, lb1, u, v0);

    kB<<<NGRP, 256, 0, stream>>>(
        pos, degArr, srcList, WT, 0,
        lb2 + 0, gb1 + 0, gb2 + 0,
        lW1 + (size_t)1 * 131 * 64, lb1 + 64,
        u, v0, v1);
    kB<<<NGRP, 256, 0, stream>>>(
        pos, degArr, srcList, WT, 1,
        lb2 + 64, gb1 + 64, gb2 + 64,
        lW1 + (size_t)2 * 131 * 64, lb1 + 128,
        u, v1, v0);
    kC<<<NGRP, 256, 0, stream>>>(
        degArr, srcList, batch, WT,
        lb2 + 128, gb1 + 128, gb2 + 128, lin1b, lin2b,
        u, v0, out);
}